// Round 13
// baseline (1522.779 us; speedup 1.0000x reference)
//
#include <hip/hip_runtime.h>
#include <math.h>

#define DEPTH 18
#define NNODES ((1 << DEPTH) - 1)
#define NINT ((1 << (DEPTH - 1)) - 1)   // internal nodes (h/c stored)
#define NVOCAB 50000

typedef unsigned short bf16raw;
typedef __bf16 bf16x8 __attribute__((ext_vector_type(8)));
typedef float f32x4 __attribute__((ext_vector_type(4)));
typedef short short8 __attribute__((ext_vector_type(8)));

__device__ __forceinline__ float sigm(float x) { return 1.0f / (1.0f + __expf(-x)); }

__device__ __forceinline__ float bf2f(bf16raw u) {
    union { unsigned int i; float f; } v;
    v.i = ((unsigned int)u) << 16;
    return v.f;
}
__device__ __forceinline__ bf16raw f2bf(float f) {
    union { float f; unsigned int i; } v;
    v.f = f;
    unsigned int r = v.i + 0x7FFFu + ((v.i >> 16) & 1u);  // RNE
    return (bf16raw)(r >> 16);
}

// ---------------------------------------------------------------------------
__global__ __launch_bounds__(256) void k_prep_embeds(const float* __restrict__ src,
                                                     bf16raw* __restrict__ dst, int n4)
{
    int i = blockIdx.x * blockDim.x + threadIdx.x;
    if (i < n4) {
        float4 v = ((const float4*)src)[i];
        ushort4 o;
        o.x = f2bf(v.x); o.y = f2bf(v.y); o.z = f2bf(v.z); o.w = f2bf(v.w);
        ((ushort4*)dst)[i] = o;
    }
}

// ---------------------------------------------------------------------------
// BcatT[col 0..639][k 0..383] bf16.  Gate order: 0=i, 1=u, 2=o, 3=f1, 4=f2
// ---------------------------------------------------------------------------
__global__ __launch_bounds__(128) void k_prep_bcat(
    const float* __restrict__ Wix, const float* __restrict__ bix,
    const float* __restrict__ Wih, const float* __restrict__ bih,
    const float* __restrict__ Wfx, const float* __restrict__ bfx,
    const float* __restrict__ Wfh, const float* __restrict__ bfh,
    const float* __restrict__ Wox, const float* __restrict__ box_,
    const float* __restrict__ Woh, const float* __restrict__ boh,
    const float* __restrict__ Wux, const float* __restrict__ bux,
    const float* __restrict__ Wuh, const float* __restrict__ buh,
    bf16raw* __restrict__ BcatT, float* __restrict__ bias_cat)
{
    const int j = blockIdx.x;        // 0..639
    const int grp = j >> 7, jj = j & 127;
    const float *Wx, *Wh, *bx, *bh;
    switch (grp) {
        case 0: Wx = Wix; Wh = Wih; bx = bix;  bh = bih; break;
        case 1: Wx = Wux; Wh = Wuh; bx = bux;  bh = buh; break;
        case 2: Wx = Wox; Wh = Woh; bx = box_; bh = boh; break;
        default: Wx = Wfx; Wh = Wfh; bx = bfx; bh = bfh; break;
    }
    for (int k = threadIdx.x; k < 384; k += blockDim.x) {
        float v;
        if (k < 128) {
            v = Wx[jj * 128 + k];
        } else if (k < 256) {
            v = (grp == 4) ? 0.f : Wh[jj * 128 + (k - 128)];
        } else {
            v = (grp == 3) ? 0.f : Wh[jj * 128 + (k - 256)];
        }
        BcatT[(long)j * 384 + k] = f2bf(v);
    }
    if (threadIdx.x == 0) bias_cat[j] = bx[jj] + bh[jj];
}

// ---------------------------------------------------------------------------
// k_leafpre: per-vocab leaf tables. hc_leaf[v][0..127]=h, [128..255]=c;
// lossv6[v][0..4]=logits, [5]=lse.
// ---------------------------------------------------------------------------
__global__ __launch_bounds__(256, 2) void k_leafpre(
    const bf16raw* __restrict__ embeds_bf,
    const bf16raw* __restrict__ BcatT, const float* __restrict__ bias_cat,
    const float* __restrict__ Wout, const float* __restrict__ bout,
    bf16raw* __restrict__ hc_leaf, float* __restrict__ lossv6, int vbase, int nv)
{
    vbase += blockIdx.x * 128;
    nv -= vbase;
    if (nv > 128) nv = 128;
    if (nv <= 0) return;

    __shared__ __align__(16) bf16raw sA[128 * 40];
    __shared__ __align__(16) bf16raw sB[128 * 40];
    __shared__ __align__(16) bf16raw sT[128 * 136];
    __shared__ float sWout[5 * 128];

    const int t = threadIdx.x;
    for (int i = t; i < 640; i += 256) sWout[i] = Wout[i];

    const int srow = t >> 1;
    const int shalf = (t & 1) * 16;
    const int arow = (srow < nv) ? srow : 0;
    const bf16raw* ax = embeds_bf + (long)(vbase + arow) * 128;

    const int lane = t & 63;
    const int w = t >> 6;
    const int wrow = (w >> 1) * 64;
    const int wcol = (w & 1) * 64;
    const int lrow = lane & 15;
    const int lquad = lane >> 4;
    const int lkoff = lquad * 8;

    float cval[4][4][4];
    unsigned int opk[4][4][2];

    for (int cb = 0; cb < 3; ++cb) {
        const bf16raw* bsrc = BcatT + ((long)(cb * 128 + srow)) * 384;
        f32x4 acc[4][4];
#pragma unroll
        for (int i = 0; i < 4; i++)
#pragma unroll
            for (int j = 0; j < 4; j++) acc[i][j] = (f32x4){0.f, 0.f, 0.f, 0.f};

        for (int kt = 0; kt < 128; kt += 32) {
            short8 av0 = *(const short8*)(ax + kt + shalf);
            short8 av1 = *(const short8*)(ax + kt + shalf + 8);
            short8 bv0 = *(const short8*)(bsrc + kt + shalf);
            short8 bv1 = *(const short8*)(bsrc + kt + shalf + 8);
            __syncthreads();
            *(short8*)&sA[srow * 40 + shalf] = av0;
            *(short8*)&sA[srow * 40 + shalf + 8] = av1;
            *(short8*)&sB[srow * 40 + shalf] = bv0;
            *(short8*)&sB[srow * 40 + shalf + 8] = bv1;
            __syncthreads();
            bf16x8 af[4], bfr[4];
#pragma unroll
            for (int i = 0; i < 4; i++) {
                af[i]  = *(const bf16x8*)&sA[(wrow + i * 16 + lrow) * 40 + lkoff];
                bfr[i] = *(const bf16x8*)&sB[(wcol + i * 16 + lrow) * 40 + lkoff];
            }
#pragma unroll
            for (int i = 0; i < 4; i++)
#pragma unroll
                for (int j = 0; j < 4; j++)
                    acc[i][j] = __builtin_amdgcn_mfma_f32_16x16x32_bf16(af[i], bfr[j], acc[i][j], 0, 0, 0);
        }
        if (cb == 0) {
#pragma unroll
            for (int i = 0; i < 4; i++)
#pragma unroll
                for (int jj = 0; jj < 4; jj++) {
                    const float bias = bias_cat[wcol + jj * 16 + lrow];
#pragma unroll
                    for (int r = 0; r < 4; r++)
                        cval[i][jj][r] = sigm(acc[i][jj][r] + bias);
                }
        } else if (cb == 1) {
#pragma unroll
            for (int i = 0; i < 4; i++)
#pragma unroll
                for (int jj = 0; jj < 4; jj++) {
                    const float bias = bias_cat[128 + wcol + jj * 16 + lrow];
#pragma unroll
                    for (int r = 0; r < 4; r++)
                        cval[i][jj][r] *= tanhf(acc[i][jj][r] + bias);
                }
        } else {
#pragma unroll
            for (int i = 0; i < 4; i++)
#pragma unroll
                for (int jj = 0; jj < 4; jj++) {
                    const float bias = bias_cat[256 + wcol + jj * 16 + lrow];
#pragma unroll
                    for (int rp = 0; rp < 2; rp++) {
                        float o0 = sigm(acc[i][jj][rp * 2] + bias);
                        float o1 = sigm(acc[i][jj][rp * 2 + 1] + bias);
                        opk[i][jj][rp] = (unsigned int)f2bf(o0) |
                                         ((unsigned int)f2bf(o1) << 16);
                    }
                }
        }
    }
    __syncthreads();
#pragma unroll
    for (int i = 0; i < 4; i++)
#pragma unroll
        for (int jj = 0; jj < 4; jj++)
#pragma unroll
            for (int r = 0; r < 4; r++) {
                const int m = wrow + i * 16 + lquad * 4 + r;
                const int j = wcol + jj * 16 + lrow;
                float o = bf2f((bf16raw)((opk[i][jj][r >> 1] >> ((r & 1) * 16)) & 0xFFFF));
                sT[m * 136 + j] = f2bf(o * tanhf(cval[i][jj][r]));
            }
    __syncthreads();
#pragma unroll
    for (int s = 0; s < 8; ++s) {
        int ci = t + 256 * s;
        int row = ci >> 4, c8 = (ci & 15) * 8;
        if (row < nv)
            *(short8*)(hc_leaf + (long)(vbase + row) * 256 + c8) = *(const short8*)&sT[row * 136 + c8];
    }
    {
        const int row = t >> 1, half = t & 1;
        float p[5] = {0.f, 0.f, 0.f, 0.f, 0.f};
        for (int k = 0; k < 64; ++k) {
            float hv = bf2f(sT[row * 136 + half * 64 + k]);
#pragma unroll
            for (int l = 0; l < 5; l++) p[l] += hv * sWout[l * 128 + half * 64 + k];
        }
#pragma unroll
        for (int l = 0; l < 5; l++) p[l] += __shfl_down(p[l], 1);
        if (half == 0 && row < nv) {
            float lg[5], mx = -1e30f;
#pragma unroll
            for (int l = 0; l < 5; l++) {
                lg[l] = p[l] + bout[l];
                mx = fmaxf(mx, lg[l]);
            }
            float se = 0.f;
#pragma unroll
            for (int l = 0; l < 5; l++) se += __expf(lg[l] - mx);
            float lse = __logf(se) + mx;
            float* dst = lossv6 + (long)(vbase + row) * 6;
#pragma unroll
            for (int l = 0; l < 5; l++) dst[l] = lg[l];
            dst[5] = lse;
        }
    }
    __syncthreads();
#pragma unroll
    for (int i = 0; i < 4; i++)
#pragma unroll
        for (int jj = 0; jj < 4; jj++)
#pragma unroll
            for (int r = 0; r < 4; r++) {
                const int m = wrow + i * 16 + lquad * 4 + r;
                const int j = wcol + jj * 16 + lrow;
                sT[m * 136 + j] = f2bf(cval[i][jj][r]);
            }
    __syncthreads();
#pragma unroll
    for (int s = 0; s < 8; ++s) {
        int ci = t + 256 * s;
        int row = ci >> 4, c8 = (ci & 15) * 8;
        if (row < nv)
            *(short8*)(hc_leaf + (long)(vbase + row) * 256 + 128 + c8) = *(const short8*)&sT[row * 136 + c8];
    }
}

// ---------------------------------------------------------------------------
// k_fused_all: one launch per internal level. Per 128-node tile:
//   5 cb x 12 kt barrier-free direct-register MFMA rounds (R12-verified
//   fragment layout), gates combined in-register (R4-verified order
//   i,u,o,f1,f2), child-c tiles staged coalesced into LDS for the f-gates,
//   h/c written coalesced via LDS, fused logits + log_softmax + loss.
// leafkids: children rows come from hc_leaf[word] (h at +0, c at +128).
// isroot: block 0 (the only block) writes out[0..4] and reduces partials.
// ---------------------------------------------------------------------------
__global__ __launch_bounds__(256) void k_fused_all(
    const bf16raw* __restrict__ embeds_bf, const int* __restrict__ words,
    bf16raw* __restrict__ h_all, bf16raw* __restrict__ c_all,
    const bf16raw* __restrict__ hc_leaf, const float* __restrict__ lossv6,
    const int* __restrict__ labels,
    const bf16raw* __restrict__ BcatT, const float* __restrict__ bias_cat,
    const float* __restrict__ Wout, const float* __restrict__ bout,
    float* __restrict__ partials, float* __restrict__ out,
    int off, int n, int leafkids, int isroot)
{
    __shared__ __align__(16) bf16raw sS[128 * 136];   // c-tile stage / h/c transpose
    __shared__ float sWout[5 * 128];
    __shared__ float sLoss;

    const int t = threadIdx.x;
    const int mbase = blockIdx.x * 128;
    const int lane = t & 63;
    const int w = t >> 6;
    const int wrow = (w >> 1) * 64;
    const int wcol = (w & 1) * 64;
    const int lrow = lane & 15;
    const int lquad = lane >> 4;

    for (int i = t; i < 640; i += 256) sWout[i] = Wout[i];
    if (t == 0) sLoss = 0.f;

    // per-lane A row pointers (4 row-frags x {x,h1,h2}); clamp OOB rows
    const bf16raw* axp[4];
    const bf16raw* h1p[4];
    const bf16raw* h2p[4];
#pragma unroll
    for (int i = 0; i < 4; i++) {
        int m = mbase + wrow + i * 16 + lrow;
        if (m >= n) m = n - 1;
        const long g = (long)off + m;
        axp[i] = embeds_bf + (long)words[g] * 128;
        if (leafkids) {
            h1p[i] = hc_leaf + (long)words[2 * g + 1] * 256;
            h2p[i] = hc_leaf + (long)words[2 * g + 2] * 256;
        } else {
            h1p[i] = h_all + (2 * g + 1) * 128;
            h2p[i] = h_all + (2 * g + 2) * 128;
        }
    }
    // staging thread assignment (2 threads/row, 16 elems each)
    const int srow = t >> 1;
    const int shalf = (t & 1) * 16;
    int msr = mbase + srow;
    if (msr >= n) msr = n - 1;
    const long gsr = (long)off + msr;

    const bf16raw* bcolBase = BcatT + ((long)(wcol + lrow)) * 384 + lquad * 8;

    float cval[4][4][4];
    unsigned int opk[4][4][2];

    for (int cb = 0; cb < 5; ++cb) {
        // stage child-c tile for f-gates (coalesced rows -> LDS)
        if (cb >= 3) {
            const int csel = cb - 3;
            const bf16raw* csrc = leafkids
                ? hc_leaf + (long)words[2 * gsr + 1 + csel] * 256 + 128
                : c_all + (2 * gsr + 1 + csel) * 128;
            short8 v0 = *(const short8*)(csrc + shalf);
            short8 v1 = *(const short8*)(csrc + shalf + 8);
            __syncthreads();   // prior sS consumers done
            *(short8*)&sS[srow * 136 + shalf] = v0;
            *(short8*)&sS[srow * 136 + shalf + 8] = v1;
            __syncthreads();
        }

        f32x4 acc[4][4];
#pragma unroll
        for (int i = 0; i < 4; i++)
#pragma unroll
            for (int j = 0; j < 4; j++) acc[i][j] = (f32x4){0.f, 0.f, 0.f, 0.f};

        const bf16raw* bcol = bcolBase + (long)cb * 128 * 384;
#pragma unroll
        for (int kt = 0; kt < 384; kt += 32) {
            const int kl = (kt & 127) + lquad * 8;
            bf16x8 af[4], bfr[4];
#pragma unroll
            for (int i = 0; i < 4; i++) {
                const bf16raw* p = (kt < 128) ? axp[i] : ((kt < 256) ? h1p[i] : h2p[i]);
                af[i]  = *(const bf16x8*)(p + kl);
                bfr[i] = *(const bf16x8*)(bcol + (long)i * 16 * 384 + kt);
            }
#pragma unroll
            for (int i = 0; i < 4; i++)
#pragma unroll
                for (int j = 0; j < 4; j++)
                    acc[i][j] = __builtin_amdgcn_mfma_f32_16x16x32_bf16(af[i], bfr[j], acc[i][j], 0, 0, 0);
        }

        // gate combine (C/D: col = lane&15 -> j, row = quad*4 + r -> m)
        if (cb == 0) {          // i
#pragma unroll
            for (int i = 0; i < 4; i++)
#pragma unroll
                for (int jj = 0; jj < 4; jj++) {
                    const float bias = bias_cat[wcol + jj * 16 + lrow];
#pragma unroll
                    for (int r = 0; r < 4; r++)
                        cval[i][jj][r] = sigm(acc[i][jj][r] + bias);
                }
        } else if (cb == 1) {   // u
#pragma unroll
            for (int i = 0; i < 4; i++)
#pragma unroll
                for (int jj = 0; jj < 4; jj++) {
                    const float bias = bias_cat[128 + wcol + jj * 16 + lrow];
#pragma unroll
                    for (int r = 0; r < 4; r++)
                        cval[i][jj][r] *= tanhf(acc[i][jj][r] + bias);
                }
        } else if (cb == 2) {   // o (stash packed bf16)
#pragma unroll
            for (int i = 0; i < 4; i++)
#pragma unroll
                for (int jj = 0; jj < 4; jj++) {
                    const float bias = bias_cat[256 + wcol + jj * 16 + lrow];
#pragma unroll
                    for (int rp = 0; rp < 2; rp++) {
                        float o0 = sigm(acc[i][jj][rp * 2] + bias);
                        float o1 = sigm(acc[i][jj][rp * 2 + 1] + bias);
                        opk[i][jj][rp] = (unsigned int)f2bf(o0) |
                                         ((unsigned int)f2bf(o1) << 16);
                    }
                }
        } else {                // f1 / f2: cval += sigm(.)*c_child (from sS)
#pragma unroll
            for (int i = 0; i < 4; i++)
#pragma unroll
                for (int jj = 0; jj < 4; jj++) {
                    const int j = wcol + jj * 16 + lrow;
                    const float bias = bias_cat[cb * 128 + j];
#pragma unroll
                    for (int r = 0; r < 4; r++) {
                        const int m = wrow + i * 16 + lquad * 4 + r;
                        cval[i][jj][r] += sigm(acc[i][jj][r] + bias)
                                        * bf2f(sS[m * 136 + j]);
                    }
                }
        }
    }

    // ----- epilogue (R4-verified pattern) -----
    __syncthreads();   // f2 sS reads done
#pragma unroll
    for (int i = 0; i < 4; i++)
#pragma unroll
        for (int jj = 0; jj < 4; jj++)
#pragma unroll
            for (int r = 0; r < 4; r++) {
                const int m = wrow + i * 16 + lquad * 4 + r;
                const int j = wcol + jj * 16 + lrow;
                float o = bf2f((bf16raw)((opk[i][jj][r >> 1] >> ((r & 1) * 16)) & 0xFFFF));
                sS[m * 136 + j] = f2bf(o * tanhf(cval[i][jj][r]));
            }
    __syncthreads();

    const long gbase = (long)off + mbase;
#pragma unroll
    for (int s = 0; s < 8; ++s) {
        int ci = t + 256 * s;
        int row = ci >> 4, c8 = (ci & 15) * 8;
        if (row < n - mbase && row < 128)
            *(short8*)(h_all + (gbase + row) * 128 + c8) = *(const short8*)&sS[row * 136 + c8];
    }
    // logits + loss (2 threads per row)
    {
        const int row = t >> 1, half = t & 1;
        float p[5] = {0.f, 0.f, 0.f, 0.f, 0.f};
        for (int k = 0; k < 64; ++k) {
            float hv = bf2f(sS[row * 136 + half * 64 + k]);
#pragma unroll
            for (int l = 0; l < 5; l++) p[l] += hv * sWout[l * 128 + half * 64 + k];
        }
#pragma unroll
        for (int l = 0; l < 5; l++) p[l] += __shfl_down(p[l], 1);
        if (half == 0 && (mbase + row) < n) {
            float lg[5], mx = -1e30f;
#pragma unroll
            for (int l = 0; l < 5; l++) {
                lg[l] = p[l] + bout[l];
                mx = fmaxf(mx, lg[l]);
            }
            float se = 0.f;
#pragma unroll
            for (int l = 0; l < 5; l++) se += __expf(lg[l] - mx);
            float lse = __logf(se) + mx;
            const long g = gbase + row;
            float lossNode = lse - lg[labels[g]];
            if (leafkids) {
                const float* lv1 = lossv6 + (long)words[2 * g + 1] * 6;
                const float* lv2 = lossv6 + (long)words[2 * g + 2] * 6;
                lossNode += (lv1[5] - lv1[labels[2 * g + 1]])
                          + (lv2[5] - lv2[labels[2 * g + 2]]);
            }
            atomicAdd(&sLoss, lossNode);
            if (isroot && g == 0) {
#pragma unroll
                for (int l = 0; l < 5; l++) out[l] = lg[l] - lse;
            }
        }
    }
    __syncthreads();
    // c scatter + write
#pragma unroll
    for (int i = 0; i < 4; i++)
#pragma unroll
        for (int jj = 0; jj < 4; jj++)
#pragma unroll
            for (int r = 0; r < 4; r++) {
                const int m = wrow + i * 16 + lquad * 4 + r;
                const int j = wcol + jj * 16 + lrow;
                sS[m * 136 + j] = f2bf(cval[i][jj][r]);
            }
    __syncthreads();
#pragma unroll
    for (int s = 0; s < 8; ++s) {
        int ci = t + 256 * s;
        int row = ci >> 4, c8 = (ci & 15) * 8;
        if (row < n - mbase && row < 128)
            *(short8*)(c_all + (gbase + row) * 128 + c8) = *(const short8*)&sS[row * 136 + c8];
    }

    if (isroot) {
        // single block: fold final loss reduction here (prior levels' partials
        // are visible across kernel boundaries; own loss comes from sLoss)
        __syncthreads();
        float s = (t == 0) ? sLoss : 0.f;
        for (int i = t; i < 1024; i += 256) s += partials[i];
#pragma unroll
        for (int d = 32; d > 0; d >>= 1) s += __shfl_down(s, d);
        float* red4 = (float*)sS;
        if ((t & 63) == 0) red4[t >> 6] = s;
        __syncthreads();
        if (t == 0) out[5] = red4[0] + red4[1] + red4[2] + red4[3];
    } else {
        if (t == 0) atomicAdd(&partials[blockIdx.x & 1023], sLoss);
    }
}

// ---------------------------------------------------------------------------
extern "C" void kernel_launch(void* const* d_in, const int* in_sizes, int n_in,
                              void* d_out, int out_size, void* d_ws, size_t ws_size,
                              hipStream_t stream)
{
    const float* embeds = (const float*)d_in[0];
    const int* words = (const int*)d_in[1];
    const int* labels = (const int*)d_in[2];
    const float* Wix = (const float*)d_in[5],  *bix  = (const float*)d_in[6];
    const float* Wih = (const float*)d_in[7],  *bih  = (const float*)d_in[8];
    const float* Wfx = (const float*)d_in[9],  *bfx  = (const float*)d_in[10];
    const float* Wfh = (const float*)d_in[11], *bfh  = (const float*)d_in[12];
    const float* Wox = (const float*)d_in[13], *box_ = (const float*)d_in[14];
    const float* Woh = (const float*)d_in[15], *boh  = (const float*)d_in[16];
    const float* Wux = (const float*)d_in[17], *bux  = (const float*)d_in[18];
    const float* Wuh = (const float*)d_in[19], *buh  = (const float*)d_in[20];
    const float* Wout = (const float*)d_in[21], *bout = (const float*)d_in[22];
    float* out = (float*)d_out;

    // Workspace (~141 MB, no G): h_all/c_all internal (33.5 MB each),
    // embeds_bf (12.8), BcatT (0.49), hc_leaf (25.6), lossv6 (1.2),
    // bias_cat, partials.
    char* ws = (char*)d_ws;
    const size_t treeElems = (size_t)NINT * 128;
    bf16raw* h_all = (bf16raw*)ws;
    bf16raw* c_all = h_all + treeElems;
    bf16raw* embeds_bf = c_all + treeElems;
    bf16raw* BcatT = embeds_bf + (size_t)NVOCAB * 128;
    bf16raw* hc_leaf = BcatT + 640 * 384;
    float* lossv6 = (float*)(hc_leaf + (size_t)NVOCAB * 256);
    float* bias_cat = lossv6 + (size_t)NVOCAB * 6;
    float* partials = bias_cat + 640;

    k_prep_embeds<<<(NVOCAB * 128 / 4 + 255) / 256, 256, 0, stream>>>(
        embeds, embeds_bf, NVOCAB * 128 / 4);
    k_prep_bcat<<<640, 128, 0, stream>>>(Wix, bix, Wih, bih, Wfx, bfx, Wfh, bfh,
                                         Wox, box_, Woh, boh, Wux, bux, Wuh, buh,
                                         BcatT, bias_cat);
    hipMemsetAsync(partials, 0, 1024 * sizeof(float), stream);

    k_leafpre<<<(NVOCAB + 127) / 128, 256, 0, stream>>>(
        embeds_bf, BcatT, bias_cat, Wout, bout, hc_leaf, lossv6, 0, NVOCAB);

    for (int l = DEPTH - 2; l >= 0; --l) {
        const int n = 1 << l;
        const int off = n - 1;
        const int leafkids = (l == DEPTH - 2) ? 1 : 0;
        const int isroot = (l == 0) ? 1 : 0;
        k_fused_all<<<(n + 127) / 128, 256, 0, stream>>>(
            embeds_bf, words, h_all, c_all, hc_leaf, lossv6, labels,
            BcatT, bias_cat, Wout, bout, partials, out, off, n, leafkids, isroot);
    }
}

// Round 15
// 700.118 us; speedup vs baseline: 2.1750x; 2.1750x over previous
//
#include <hip/hip_runtime.h>
#include <math.h>

#define DEPTH 18
#define NNODES ((1 << DEPTH) - 1)
#define NINT ((1 << (DEPTH - 1)) - 1)   // internal nodes (h/c stored)
#define NVOCAB 50000

typedef unsigned short bf16raw;
typedef __bf16 bf16x8 __attribute__((ext_vector_type(8)));
typedef float f32x4 __attribute__((ext_vector_type(4)));
typedef short short8 __attribute__((ext_vector_type(8)));

__device__ __forceinline__ float sigm(float x) { return 1.0f / (1.0f + __expf(-x)); }

__device__ __forceinline__ float bf2f(bf16raw u) {
    union { unsigned int i; float f; } v;
    v.i = ((unsigned int)u) << 16;
    return v.f;
}
__device__ __forceinline__ bf16raw f2bf(float f) {
    union { float f; unsigned int i; } v;
    v.f = f;
    unsigned int r = v.i + 0x7FFFu + ((v.i >> 16) & 1u);  // RNE
    return (bf16raw)(r >> 16);
}

// ---------------------------------------------------------------------------
__global__ __launch_bounds__(256) void k_prep_embeds(const float* __restrict__ src,
                                                     bf16raw* __restrict__ dst, int n4)
{
    int i = blockIdx.x * blockDim.x + threadIdx.x;
    if (i < n4) {
        float4 v = ((const float4*)src)[i];
        ushort4 o;
        o.x = f2bf(v.x); o.y = f2bf(v.y); o.z = f2bf(v.z); o.w = f2bf(v.w);
        ((ushort4*)dst)[i] = o;
    }
}

// ---------------------------------------------------------------------------
// BcatT[col 0..639][k 0..383] bf16.  Gate order: 0=i, 1=u, 2=o, 3=f1, 4=f2
// ---------------------------------------------------------------------------
__global__ __launch_bounds__(128) void k_prep_bcat(
    const float* __restrict__ Wix, const float* __restrict__ bix,
    const float* __restrict__ Wih, const float* __restrict__ bih,
    const float* __restrict__ Wfx, const float* __restrict__ bfx,
    const float* __restrict__ Wfh, const float* __restrict__ bfh,
    const float* __restrict__ Wox, const float* __restrict__ box_,
    const float* __restrict__ Woh, const float* __restrict__ boh,
    const float* __restrict__ Wux, const float* __restrict__ bux,
    const float* __restrict__ Wuh, const float* __restrict__ buh,
    bf16raw* __restrict__ BcatT, float* __restrict__ bias_cat)
{
    const int j = blockIdx.x;        // 0..639
    const int grp = j >> 7, jj = j & 127;
    const float *Wx, *Wh, *bx, *bh;
    switch (grp) {
        case 0: Wx = Wix; Wh = Wih; bx = bix;  bh = bih; break;
        case 1: Wx = Wux; Wh = Wuh; bx = bux;  bh = buh; break;
        case 2: Wx = Wox; Wh = Woh; bx = box_; bh = boh; break;
        default: Wx = Wfx; Wh = Wfh; bx = bfx; bh = bfh; break;
    }
    for (int k = threadIdx.x; k < 384; k += blockDim.x) {
        float v;
        if (k < 128) {
            v = Wx[jj * 128 + k];
        } else if (k < 256) {
            v = (grp == 4) ? 0.f : Wh[jj * 128 + (k - 128)];
        } else {
            v = (grp == 3) ? 0.f : Wh[jj * 128 + (k - 256)];
        }
        BcatT[(long)j * 384 + k] = f2bf(v);
    }
    if (threadIdx.x == 0) bias_cat[j] = bx[jj] + bh[jj];
}

// ---------------------------------------------------------------------------
// k_leafpre: per-vocab leaf tables. hc_leaf[v][0..127]=h, [128..255]=c;
// lossv6[v][0..4]=logits, [5]=lse.
// ---------------------------------------------------------------------------
__global__ __launch_bounds__(256, 2) void k_leafpre(
    const bf16raw* __restrict__ embeds_bf,
    const bf16raw* __restrict__ BcatT, const float* __restrict__ bias_cat,
    const float* __restrict__ Wout, const float* __restrict__ bout,
    bf16raw* __restrict__ hc_leaf, float* __restrict__ lossv6, int vbase, int nv)
{
    vbase += blockIdx.x * 128;
    nv -= vbase;
    if (nv > 128) nv = 128;
    if (nv <= 0) return;

    __shared__ __align__(16) bf16raw sA[128 * 40];
    __shared__ __align__(16) bf16raw sB[128 * 40];
    __shared__ __align__(16) bf16raw sT[128 * 136];
    __shared__ float sWout[5 * 128];

    const int t = threadIdx.x;
    for (int i = t; i < 640; i += 256) sWout[i] = Wout[i];

    const int srow = t >> 1;
    const int shalf = (t & 1) * 16;
    const int arow = (srow < nv) ? srow : 0;
    const bf16raw* ax = embeds_bf + (long)(vbase + arow) * 128;

    const int lane = t & 63;
    const int w = t >> 6;
    const int wrow = (w >> 1) * 64;
    const int wcol = (w & 1) * 64;
    const int lrow = lane & 15;
    const int lquad = lane >> 4;
    const int lkoff = lquad * 8;

    float cval[4][4][4];
    unsigned int opk[4][4][2];

    for (int cb = 0; cb < 3; ++cb) {
        const bf16raw* bsrc = BcatT + ((long)(cb * 128 + srow)) * 384;
        f32x4 acc[4][4];
#pragma unroll
        for (int i = 0; i < 4; i++)
#pragma unroll
            for (int j = 0; j < 4; j++) acc[i][j] = (f32x4){0.f, 0.f, 0.f, 0.f};

        for (int kt = 0; kt < 128; kt += 32) {
            short8 av0 = *(const short8*)(ax + kt + shalf);
            short8 av1 = *(const short8*)(ax + kt + shalf + 8);
            short8 bv0 = *(const short8*)(bsrc + kt + shalf);
            short8 bv1 = *(const short8*)(bsrc + kt + shalf + 8);
            __syncthreads();
            *(short8*)&sA[srow * 40 + shalf] = av0;
            *(short8*)&sA[srow * 40 + shalf + 8] = av1;
            *(short8*)&sB[srow * 40 + shalf] = bv0;
            *(short8*)&sB[srow * 40 + shalf + 8] = bv1;
            __syncthreads();
            bf16x8 af[4], bfr[4];
#pragma unroll
            for (int i = 0; i < 4; i++) {
                af[i]  = *(const bf16x8*)&sA[(wrow + i * 16 + lrow) * 40 + lkoff];
                bfr[i] = *(const bf16x8*)&sB[(wcol + i * 16 + lrow) * 40 + lkoff];
            }
#pragma unroll
            for (int i = 0; i < 4; i++)
#pragma unroll
                for (int j = 0; j < 4; j++)
                    acc[i][j] = __builtin_amdgcn_mfma_f32_16x16x32_bf16(af[i], bfr[j], acc[i][j], 0, 0, 0);
        }
        if (cb == 0) {
#pragma unroll
            for (int i = 0; i < 4; i++)
#pragma unroll
                for (int jj = 0; jj < 4; jj++) {
                    const float bias = bias_cat[wcol + jj * 16 + lrow];
#pragma unroll
                    for (int r = 0; r < 4; r++)
                        cval[i][jj][r] = sigm(acc[i][jj][r] + bias);
                }
        } else if (cb == 1) {
#pragma unroll
            for (int i = 0; i < 4; i++)
#pragma unroll
                for (int jj = 0; jj < 4; jj++) {
                    const float bias = bias_cat[128 + wcol + jj * 16 + lrow];
#pragma unroll
                    for (int r = 0; r < 4; r++)
                        cval[i][jj][r] *= tanhf(acc[i][jj][r] + bias);
                }
        } else {
#pragma unroll
            for (int i = 0; i < 4; i++)
#pragma unroll
                for (int jj = 0; jj < 4; jj++) {
                    const float bias = bias_cat[256 + wcol + jj * 16 + lrow];
#pragma unroll
                    for (int rp = 0; rp < 2; rp++) {
                        float o0 = sigm(acc[i][jj][rp * 2] + bias);
                        float o1 = sigm(acc[i][jj][rp * 2 + 1] + bias);
                        opk[i][jj][rp] = (unsigned int)f2bf(o0) |
                                         ((unsigned int)f2bf(o1) << 16);
                    }
                }
        }
    }
    __syncthreads();
#pragma unroll
    for (int i = 0; i < 4; i++)
#pragma unroll
        for (int jj = 0; jj < 4; jj++)
#pragma unroll
            for (int r = 0; r < 4; r++) {
                const int m = wrow + i * 16 + lquad * 4 + r;
                const int j = wcol + jj * 16 + lrow;
                float o = bf2f((bf16raw)((opk[i][jj][r >> 1] >> ((r & 1) * 16)) & 0xFFFF));
                sT[m * 136 + j] = f2bf(o * tanhf(cval[i][jj][r]));
            }
    __syncthreads();
#pragma unroll
    for (int s = 0; s < 8; ++s) {
        int ci = t + 256 * s;
        int row = ci >> 4, c8 = (ci & 15) * 8;
        if (row < nv)
            *(short8*)(hc_leaf + (long)(vbase + row) * 256 + c8) = *(const short8*)&sT[row * 136 + c8];
    }
    {
        const int row = t >> 1, half = t & 1;
        float p[5] = {0.f, 0.f, 0.f, 0.f, 0.f};
        for (int k = 0; k < 64; ++k) {
            float hv = bf2f(sT[row * 136 + half * 64 + k]);
#pragma unroll
            for (int l = 0; l < 5; l++) p[l] += hv * sWout[l * 128 + half * 64 + k];
        }
#pragma unroll
        for (int l = 0; l < 5; l++) p[l] += __shfl_down(p[l], 1);
        if (half == 0 && row < nv) {
            float lg[5], mx = -1e30f;
#pragma unroll
            for (int l = 0; l < 5; l++) {
                lg[l] = p[l] + bout[l];
                mx = fmaxf(mx, lg[l]);
            }
            float se = 0.f;
#pragma unroll
            for (int l = 0; l < 5; l++) se += __expf(lg[l] - mx);
            float lse = __logf(se) + mx;
            float* dst = lossv6 + (long)(vbase + row) * 6;
#pragma unroll
            for (int l = 0; l < 5; l++) dst[l] = lg[l];
            dst[5] = lse;
        }
    }
    __syncthreads();
#pragma unroll
    for (int i = 0; i < 4; i++)
#pragma unroll
        for (int jj = 0; jj < 4; jj++)
#pragma unroll
            for (int r = 0; r < 4; r++) {
                const int m = wrow + i * 16 + lquad * 4 + r;
                const int j = wcol + jj * 16 + lrow;
                sT[m * 136 + j] = f2bf(cval[i][jj][r]);
            }
    __syncthreads();
#pragma unroll
    for (int s = 0; s < 8; ++s) {
        int ci = t + 256 * s;
        int row = ci >> 4, c8 = (ci & 15) * 8;
        if (row < nv)
            *(short8*)(hc_leaf + (long)(vbase + row) * 256 + 128 + c8) = *(const short8*)&sT[row * 136 + c8];
    }
}

// ---------------------------------------------------------------------------
// k_gemm (levels 16..13, LDS-staged): G = [x|h1|h2].BcatT^T + bias.
// ---------------------------------------------------------------------------
__global__ __launch_bounds__(256) void k_gemm(
    const bf16raw* __restrict__ embeds_bf, const int* __restrict__ words,
    const bf16raw* __restrict__ h_all, const bf16raw* __restrict__ hc_leaf,
    const bf16raw* __restrict__ BcatT, const float* __restrict__ bias_cat,
    bf16raw* __restrict__ G, int off, int m0, int nm, int leafkids)
{
    __shared__ __align__(16) bf16raw sA[128 * 40];
    __shared__ __align__(16) bf16raw sB[128 * 40];
    __shared__ __align__(16) bf16raw sT[128 * 76];

    const int t = threadIdx.x;
    const int cb = blockIdx.x;
    const int mbase = blockIdx.y * 128;

    const int srow = t >> 1;
    const int shalf = (t & 1) * 16;
    const long glr = (long)off + m0 + mbase + srow;
    const bf16raw* ax = embeds_bf + (long)words[glr] * 128;
    const bf16raw *ah1, *ah2;
    if (leafkids) {
        ah1 = hc_leaf + (long)words[2 * glr + 1] * 256;
        ah2 = hc_leaf + (long)words[2 * glr + 2] * 256;
    } else {
        ah1 = h_all + (2 * glr + 1) * 128;
        ah2 = h_all + (2 * glr + 2) * 128;
    }
    const bf16raw* bsrc = BcatT + ((long)(cb * 128 + srow)) * 384;

    const int lane = t & 63;
    const int w = t >> 6;
    const int wrow = (w >> 1) * 64;
    const int wcol = (w & 1) * 64;
    const int lrow = lane & 15;
    const int lquad = lane >> 4;
    const int lkoff = lquad * 8;

    f32x4 acc[4][4];
#pragma unroll
    for (int i = 0; i < 4; i++)
#pragma unroll
        for (int j = 0; j < 4; j++) acc[i][j] = (f32x4){0.f, 0.f, 0.f, 0.f};

    for (int kt = 0; kt < 384; kt += 32) {
        const bf16raw* asrc = (kt < 128) ? ax : ((kt < 256) ? ah1 : ah2);
        const int kl = kt & 127;
        short8 av0 = *(const short8*)(asrc + kl + shalf);
        short8 av1 = *(const short8*)(asrc + kl + shalf + 8);
        short8 bv0 = *(const short8*)(bsrc + kt + shalf);
        short8 bv1 = *(const short8*)(bsrc + kt + shalf + 8);
        __syncthreads();
        *(short8*)&sA[srow * 40 + shalf] = av0;
        *(short8*)&sA[srow * 40 + shalf + 8] = av1;
        *(short8*)&sB[srow * 40 + shalf] = bv0;
        *(short8*)&sB[srow * 40 + shalf + 8] = bv1;
        __syncthreads();
        bf16x8 af[4], bfr[4];
#pragma unroll
        for (int i = 0; i < 4; i++) {
            af[i]  = *(const bf16x8*)&sA[(wrow + i * 16 + lrow) * 40 + lkoff];
            bfr[i] = *(const bf16x8*)&sB[(wcol + i * 16 + lrow) * 40 + lkoff];
        }
#pragma unroll
        for (int i = 0; i < 4; i++)
#pragma unroll
            for (int j = 0; j < 4; j++)
                acc[i][j] = __builtin_amdgcn_mfma_f32_16x16x32_bf16(af[i], bfr[j], acc[i][j], 0, 0, 0);
    }

    float bias[4];
#pragma unroll
    for (int jj = 0; jj < 4; jj++)
        bias[jj] = bias_cat[cb * 128 + wcol + jj * 16 + lrow];

#pragma unroll
    for (int half = 0; half < 2; ++half) {
        __syncthreads();
        if ((wcol >> 6) == half) {
#pragma unroll
            for (int i = 0; i < 4; i++)
#pragma unroll
                for (int jj = 0; jj < 4; jj++)
#pragma unroll
                    for (int r = 0; r < 4; r++)
                        sT[(wrow + i * 16 + lquad * 4 + r) * 76 + jj * 16 + lrow] =
                            f2bf(acc[i][jj][r] + bias[jj]);
        }
        __syncthreads();
#pragma unroll
        for (int s = 0; s < 4; ++s) {
            int ci = t + 256 * s;
            int row = ci >> 3, c8 = (ci & 7) * 8;
            int m = mbase + row;
            if (m < nm)
                *(short8*)(G + (long)m * 640 + cb * 128 + half * 64 + c8) =
                    *(const short8*)&sT[row * 76 + c8];
        }
    }
}

// ---------------------------------------------------------------------------
// k_gemm_direct (levels <=12): barrier-free K-loop. Each lane loads its MFMA
// A/B fragments directly from global (L2/L3-hot at these sizes) in fragment
// layout; no LDS staging, no __syncthreads in the K-loop, so all loads are
// independent and pipeline. LDS used only for the coalesced store epilogue.
// ---------------------------------------------------------------------------
__global__ __launch_bounds__(256) void k_gemm_direct(
    const bf16raw* __restrict__ embeds_bf, const int* __restrict__ words,
    const bf16raw* __restrict__ h_all,
    const bf16raw* __restrict__ BcatT, const float* __restrict__ bias_cat,
    bf16raw* __restrict__ G, int off, int nm)
{
    __shared__ __align__(16) bf16raw sT[128 * 76];

    const int t = threadIdx.x;
    const int cb = blockIdx.x;
    const int mbase = blockIdx.y * 128;
    const int lane = t & 63;
    const int w = t >> 6;
    const int wrow = (w >> 1) * 64;
    const int wcol = (w & 1) * 64;
    const int lrow = lane & 15;
    const int lquad = lane >> 4;

    // per-lane A row pointers: 4 row-frags x {x, h1, h2}
    const bf16raw* axp[4];
    const bf16raw* h1p[4];
    const bf16raw* h2p[4];
#pragma unroll
    for (int i = 0; i < 4; i++) {
        int m = mbase + wrow + i * 16 + lrow;
        if (m >= nm) m = nm - 1;           // clamp; stores masked in epilogue
        const long g = (long)off + m;
        axp[i] = embeds_bf + (long)words[g] * 128;
        h1p[i] = h_all + (2 * g + 1) * 128;
        h2p[i] = h_all + (2 * g + 2) * 128;
    }
    const bf16raw* bcol = BcatT + ((long)(cb * 128 + wcol + lrow)) * 384 + lquad * 8;

    f32x4 acc[4][4];
#pragma unroll
    for (int i = 0; i < 4; i++)
#pragma unroll
        for (int j = 0; j < 4; j++) acc[i][j] = (f32x4){0.f, 0.f, 0.f, 0.f};

#pragma unroll
    for (int kt = 0; kt < 384; kt += 32) {
        const int kl = (kt & 127) + lquad * 8;
        bf16x8 af[4], bfr[4];
#pragma unroll
        for (int i = 0; i < 4; i++) {
            const bf16raw* p = (kt < 128) ? axp[i] : ((kt < 256) ? h1p[i] : h2p[i]);
            af[i]  = *(const bf16x8*)(p + kl);
            bfr[i] = *(const bf16x8*)(bcol + (long)i * 16 * 384 + kt);
        }
#pragma unroll
        for (int i = 0; i < 4; i++)
#pragma unroll
            for (int j = 0; j < 4; j++)
                acc[i][j] = __builtin_amdgcn_mfma_f32_16x16x32_bf16(af[i], bfr[j], acc[i][j], 0, 0, 0);
    }

    float bias[4];
#pragma unroll
    for (int jj = 0; jj < 4; jj++)
        bias[jj] = bias_cat[cb * 128 + wcol + jj * 16 + lrow];

#pragma unroll
    for (int half = 0; half < 2; ++half) {
        __syncthreads();
        if ((wcol >> 6) == half) {
#pragma unroll
            for (int i = 0; i < 4; i++)
#pragma unroll
                for (int jj = 0; jj < 4; jj++)
#pragma unroll
                    for (int r = 0; r < 4; r++)
                        sT[(wrow + i * 16 + lquad * 4 + r) * 76 + jj * 16 + lrow] =
                            f2bf(acc[i][jj][r] + bias[jj]);
        }
        __syncthreads();
#pragma unroll
        for (int s = 0; s < 4; ++s) {
            int ci = t + 256 * s;
            int row = ci >> 3, c8 = (ci & 7) * 8;
            int m = mbase + row;
            if (m < nm)
                *(short8*)(G + (long)m * 640 + cb * 128 + half * 64 + c8) =
                    *(const short8*)&sT[row * 76 + c8];
        }
    }
}

// ---------------------------------------------------------------------------
// k_gates: one 128-thread block per node. Gate order i,u,o,f1,f2.
// leafkids: c children from hc_leaf; leaf-children loss terms folded in.
// ---------------------------------------------------------------------------
__global__ __launch_bounds__(128) void k_gates(
    const bf16raw* __restrict__ G,
    bf16raw* __restrict__ h_all, bf16raw* __restrict__ c_all,
    const int* __restrict__ words, const int* __restrict__ labels,
    const bf16raw* __restrict__ hc_leaf, const float* __restrict__ lossv6,
    const float* __restrict__ Wout, const float* __restrict__ bout,
    float* __restrict__ partials, float* __restrict__ out,
    int off, int m0, int leafkids, int isroot)
{
    const int m = blockIdx.x;
    const int j = threadIdx.x;
    const long g = (long)off + m0 + m;
    const bf16raw* Grow = G + (long)m * 640;

    float c1, c2;
    if (leafkids) {
        c1 = bf2f(hc_leaf[(long)words[2 * g + 1] * 256 + 128 + j]);
        c2 = bf2f(hc_leaf[(long)words[2 * g + 2] * 256 + 128 + j]);
    } else {
        c1 = bf2f(c_all[(2 * g + 1) * 128 + j]);
        c2 = bf2f(c_all[(2 * g + 2) * 128 + j]);
    }

    float iv = sigm(bf2f(Grow[j]));
    float uv = tanhf(bf2f(Grow[128 + j]));
    float ov = sigm(bf2f(Grow[256 + j]));
    float f1 = sigm(bf2f(Grow[384 + j]));
    float f2 = sigm(bf2f(Grow[512 + j]));
    float c = iv * uv + f1 * c1 + f2 * c2;
    float h = ov * tanhf(c);
    h_all[g * 128 + j] = f2bf(h);
    c_all[g * 128 + j] = f2bf(c);

    float p0 = h * Wout[j];
    float p1 = h * Wout[128 + j];
    float p2 = h * Wout[256 + j];
    float p3 = h * Wout[384 + j];
    float p4 = h * Wout[512 + j];
#pragma unroll
    for (int s = 32; s > 0; s >>= 1) {
        p0 += __shfl_down(p0, s);
        p1 += __shfl_down(p1, s);
        p2 += __shfl_down(p2, s);
        p3 += __shfl_down(p3, s);
        p4 += __shfl_down(p4, s);
    }
    __shared__ float red[2][5];
    if ((j & 63) == 0) {
        int wv = j >> 6;
        red[wv][0] = p0; red[wv][1] = p1; red[wv][2] = p2; red[wv][3] = p3; red[wv][4] = p4;
    }
    __syncthreads();
    if (j == 0) {
        float lg[5], mx = -1e30f;
#pragma unroll
        for (int l = 0; l < 5; l++) {
            lg[l] = red[0][l] + red[1][l] + bout[l];
            mx = fmaxf(mx, lg[l]);
        }
        float se = 0.f;
#pragma unroll
        for (int l = 0; l < 5; l++) se += __expf(lg[l] - mx);
        float lse = __logf(se) + mx;
        float lossNode = lse - lg[labels[g]];
        if (leafkids) {
            const float* lv1 = lossv6 + (long)words[2 * g + 1] * 6;
            const float* lv2 = lossv6 + (long)words[2 * g + 2] * 6;
            lossNode += (lv1[5] - lv1[labels[2 * g + 1]])
                      + (lv2[5] - lv2[labels[2 * g + 2]]);
        }
        atomicAdd(&partials[m & 1023], lossNode);
        if (isroot) {
#pragma unroll
            for (int l = 0; l < 5; l++) out[l] = lg[l] - lse;
        }
    }
}

__global__ __launch_bounds__(256) void k3_reduce(const float* __restrict__ partials,
                                                 float* __restrict__ out)
{
    const int t = threadIdx.x;
    float s = 0.f;
    for (int i = t; i < 1024; i += 256) s += partials[i];
#pragma unroll
    for (int d = 32; d > 0; d >>= 1) s += __shfl_down(s, d);
    __shared__ float red[4];
    if ((t & 63) == 0) red[t >> 6] = s;
    __syncthreads();
    if (t == 0) out[5] = red[0] + red[1] + red[2] + red[3];
}

// ---------------------------------------------------------------------------
extern "C" void kernel_launch(void* const* d_in, const int* in_sizes, int n_in,
                              void* d_out, int out_size, void* d_ws, size_t ws_size,
                              hipStream_t stream)
{
    const float* embeds = (const float*)d_in[0];
    const int* words = (const int*)d_in[1];
    const int* labels = (const int*)d_in[2];
    const float* Wix = (const float*)d_in[5],  *bix  = (const float*)d_in[6];
    const float* Wih = (const float*)d_in[7],  *bih  = (const float*)d_in[8];
    const float* Wfx = (const float*)d_in[9],  *bfx  = (const float*)d_in[10];
    const float* Wfh = (const float*)d_in[11], *bfh  = (const float*)d_in[12];
    const float* Wox = (const float*)d_in[13], *box_ = (const float*)d_in[14];
    const float* Woh = (const float*)d_in[15], *boh  = (const float*)d_in[16];
    const float* Wux = (const float*)d_in[17], *bux  = (const float*)d_in[18];
    const float* Wuh = (const float*)d_in[19], *buh  = (const float*)d_in[20];
    const float* Wout = (const float*)d_in[21], *bout = (const float*)d_in[22];
    float* out = (float*)d_out;

    char* ws = (char*)d_ws;
    const size_t treeElems = (size_t)NINT * 128;
    bf16raw* h_all = (bf16raw*)ws;
    bf16raw* c_all = h_all + treeElems;
    bf16raw* embeds_bf = c_all + treeElems;
    bf16raw* BcatT = embeds_bf + (size_t)NVOCAB * 128;
    bf16raw* hc_leaf = BcatT + 640 * 384;
    float* lossv6 = (float*)(hc_leaf + (size_t)NVOCAB * 256);
    float* bias_cat = lossv6 + (size_t)NVOCAB * 6;
    float* partials = bias_cat + 640;
    bf16raw* G = (bf16raw*)(partials + 1024);

    const size_t fixedBytes = (char*)G - ws;
    size_t avail = (ws_size > fixedBytes) ? (ws_size - fixedBytes) : 0;
    long cap = (long)(avail / (640 * sizeof(bf16raw)));
    int chunk = (int)((cap / 128) * 128);
    if (chunk < 128) chunk = 128;
    if (chunk > 65536) chunk = 65536;

    k_prep_embeds<<<(NVOCAB * 128 / 4 + 255) / 256, 256, 0, stream>>>(
        embeds, embeds_bf, NVOCAB * 128 / 4);
    k_prep_bcat<<<640, 128, 0, stream>>>(Wix, bix, Wih, bih, Wfx, bfx, Wfh, bfh,
                                         Wox, box_, Woh, boh, Wux, bux, Wuh, buh,
                                         BcatT, bias_cat);
    hipMemsetAsync(partials, 0, 1024 * sizeof(float), stream);

    k_leafpre<<<(NVOCAB + 127) / 128, 256, 0, stream>>>(
        embeds_bf, BcatT, bias_cat, Wout, bout, hc_leaf, lossv6, 0, NVOCAB);

    for (int l = DEPTH - 2; l >= 0; --l) {
        const int n = 1 << l;
        const int off = n - 1;
        const int leafkids = (l == DEPTH - 2) ? 1 : 0;
        const int isroot = (l == 0) ? 1 : 0;
        if (l >= 13) {
            for (int m0 = 0; m0 < n; m0 += chunk) {
                const int nm = (n - m0 < chunk) ? (n - m0) : chunk;
                dim3 g1(5, (nm + 127) / 128);
                k_gemm<<<g1, 256, 0, stream>>>(embeds_bf, words, h_all, hc_leaf,
                                               BcatT, bias_cat, G, off, m0, nm, leafkids);
                k_gates<<<nm, 128, 0, stream>>>(G, h_all, c_all, words, labels,
                                                hc_leaf, lossv6, Wout, bout,
                                                partials, out, off, m0, leafkids, isroot);
            }
        } else {
            dim3 g1(5, (n + 127) / 128);
            k_gemm_direct<<<g1, 256, 0, stream>>>(embeds_bf, words, h_all,
                                                  BcatT, bias_cat, G, off, n);
            k_gates<<<n, 128, 0, stream>>>(G, h_all, c_all, words, labels,
                                           hc_leaf, lossv6, Wout, bout,
                                           partials, out, off, 0, 0, isroot);
        }
    }
    k3_reduce<<<1, 256, 0, stream>>>(partials, out);
}